// Round 1
// baseline (368.086 us; speedup 1.0000x reference)
//
#include <hip/hip_runtime.h>
#include <hip/hip_bf16.h>

#define N_NODES 50000
#define N_EDGES 800000
#define N_FEAT 512
#define HIDDEN 128
#define N_CLASSES 32

// ---------------- CSR build ----------------

__global__ __launch_bounds__(256) void hist_k(const int* __restrict__ src, int* __restrict__ cnt) {
    int i = blockIdx.x * 256 + threadIdx.x;
    if (i < N_EDGES) atomicAdd(&cnt[src[i]], 1);
}

__global__ __launch_bounds__(256) void scan_a(const int* __restrict__ cnt, int* __restrict__ bsum) {
    __shared__ int sd[256];
    int t = threadIdx.x;
    int i = blockIdx.x * 256 + t;
    sd[t] = (i < N_NODES) ? cnt[i] : 0;
    __syncthreads();
    for (int off = 128; off > 0; off >>= 1) {
        if (t < off) sd[t] += sd[t + off];
        __syncthreads();
    }
    if (t == 0) bsum[blockIdx.x] = sd[0];
}

__global__ __launch_bounds__(256) void scan_b(const int* __restrict__ bsum, int* __restrict__ boff) {
    __shared__ int sd[256];
    int t = threadIdx.x;
    int v = (t < 196) ? bsum[t] : 0;
    sd[t] = v;
    __syncthreads();
    for (int off = 1; off < 256; off <<= 1) {
        int xv = (t >= off) ? sd[t - off] : 0;
        __syncthreads();
        sd[t] += xv;
        __syncthreads();
    }
    if (t < 196) boff[t] = sd[t] - v;   // exclusive
}

// cnt may alias cursor (each thread reads its own element then writes it) — no __restrict__
__global__ __launch_bounds__(256) void scan_c(const int* cnt, const int* boff,
                                              int* row_ptr, int* cursor) {
    __shared__ int sd[256];
    int t = threadIdx.x;
    int i = blockIdx.x * 256 + t;
    int v = (i < N_NODES) ? cnt[i] : 0;
    sd[t] = v;
    __syncthreads();
    for (int off = 1; off < 256; off <<= 1) {
        int xv = (t >= off) ? sd[t - off] : 0;
        __syncthreads();
        sd[t] += xv;
        __syncthreads();
    }
    int start = boff[blockIdx.x] + (sd[t] - v);
    if (i < N_NODES) { row_ptr[i] = start; cursor[i] = start; }
    if (i == N_NODES) row_ptr[N_NODES] = N_EDGES;
}

__global__ __launch_bounds__(256) void scatter_k(const int* __restrict__ src, const int* __restrict__ dst,
                                                 const float* __restrict__ val, int* __restrict__ cursor,
                                                 int* __restrict__ csr_dst, float* __restrict__ csr_val) {
    int i = blockIdx.x * 256 + threadIdx.x;
    if (i >= N_EDGES) return;
    int s = src[i];
    int pos = atomicAdd(&cursor[s], 1);
    csr_dst[pos] = dst[i];
    csr_val[pos] = val[i];
}

// ---------------- GEMM1: pre1[50000,128] = x[50000,512] @ W1[512,128] (f32 vector) ----------------

__global__ __launch_bounds__(256) void gemm1_k(const float* __restrict__ x,
                                               const float* __restrict__ W1,
                                               float* __restrict__ pre1) {
    __shared__ float xs[64][68];     // stride 68: 16B aligned, a-reads 2-way (free)
    __shared__ float wsh[64][HIDDEN];
    const int t = threadIdx.x;
    const int row0 = blockIdx.x * 64;
    const int tr = t >> 4;           // 0..15 -> rows tr*4..tr*4+3
    const int tc = t & 15;           // 0..15 -> cols 4tc..4tc+3 and 64+4tc..

    float acc[4][8];
#pragma unroll
    for (int i = 0; i < 4; ++i)
#pragma unroll
        for (int j = 0; j < 8; ++j) acc[i][j] = 0.f;

    const int lr = t >> 2;            // 0..63
    const int lk = (t & 3) << 4;      // 0,16,32,48
    int gr = row0 + lr;
    if (gr >= N_NODES) gr = N_NODES - 1;   // clamp (writes are guarded)
    const float* xrow = x + (size_t)gr * N_FEAT;

    for (int k0 = 0; k0 < N_FEAT; k0 += 64) {
        __syncthreads();
        // stage x tile: 64 rows x 64 k
#pragma unroll
        for (int j = 0; j < 4; ++j) {
            float4 v = *(const float4*)(xrow + k0 + lk + 4 * j);
            *(float4*)&xs[lr][lk + 4 * j] = v;
        }
        // stage W1 tile: 64 x 128  (2048 float4, coalesced: f = j*256+t)
#pragma unroll
        for (int j = 0; j < 8; ++j) {
            int f = j * 256 + t;
            int wr = f >> 5;
            int wc = (f & 31) << 2;
            float4 v = *(const float4*)(W1 + (size_t)(k0 + wr) * HIDDEN + wc);
            *(float4*)&wsh[wr][wc] = v;
        }
        __syncthreads();
#pragma unroll 16
        for (int kk = 0; kk < 64; ++kk) {
            float a0 = xs[tr * 4 + 0][kk];
            float a1 = xs[tr * 4 + 1][kk];
            float a2 = xs[tr * 4 + 2][kk];
            float a3 = xs[tr * 4 + 3][kk];
            float4 b0 = *(const float4*)&wsh[kk][tc << 2];
            float4 b1 = *(const float4*)&wsh[kk][64 + (tc << 2)];
            acc[0][0] += a0 * b0.x; acc[0][1] += a0 * b0.y; acc[0][2] += a0 * b0.z; acc[0][3] += a0 * b0.w;
            acc[0][4] += a0 * b1.x; acc[0][5] += a0 * b1.y; acc[0][6] += a0 * b1.z; acc[0][7] += a0 * b1.w;
            acc[1][0] += a1 * b0.x; acc[1][1] += a1 * b0.y; acc[1][2] += a1 * b0.z; acc[1][3] += a1 * b0.w;
            acc[1][4] += a1 * b1.x; acc[1][5] += a1 * b1.y; acc[1][6] += a1 * b1.z; acc[1][7] += a1 * b1.w;
            acc[2][0] += a2 * b0.x; acc[2][1] += a2 * b0.y; acc[2][2] += a2 * b0.z; acc[2][3] += a2 * b0.w;
            acc[2][4] += a2 * b1.x; acc[2][5] += a2 * b1.y; acc[2][6] += a2 * b1.z; acc[2][7] += a2 * b1.w;
            acc[3][0] += a3 * b0.x; acc[3][1] += a3 * b0.y; acc[3][2] += a3 * b0.z; acc[3][3] += a3 * b0.w;
            acc[3][4] += a3 * b1.x; acc[3][5] += a3 * b1.y; acc[3][6] += a3 * b1.z; acc[3][7] += a3 * b1.w;
        }
    }
#pragma unroll
    for (int i = 0; i < 4; ++i) {
        int r = row0 + tr * 4 + i;
        if (r < N_NODES) {
            float4 o0 = make_float4(acc[i][0], acc[i][1], acc[i][2], acc[i][3]);
            float4 o1 = make_float4(acc[i][4], acc[i][5], acc[i][6], acc[i][7]);
            *(float4*)(pre1 + (size_t)r * HIDDEN + (tc << 2)) = o0;
            *(float4*)(pre1 + (size_t)r * HIDDEN + 64 + (tc << 2)) = o1;
        }
    }
}

// ---------------- SpMM1: h = relu(A @ pre1), one wave per node, float2/lane ----------------

__global__ __launch_bounds__(256) void spmm1_k(const int* __restrict__ rp, const int* __restrict__ cd,
                                               const float* __restrict__ cv, const float* __restrict__ pre1,
                                               float* __restrict__ h) {
    const int g = threadIdx.x >> 6;
    const int lane = threadIdx.x & 63;
    const int node = blockIdx.x * 4 + g;
    if (node >= N_NODES) return;
    const int s = rp[node], e = rp[node + 1];
    const float2* __restrict__ P = (const float2*)pre1;
    float2 acc; acc.x = 0.f; acc.y = 0.f;
    for (int i = s; i < e; ++i) {
        int dst = cd[i];
        float v = cv[i];
        float2 p = P[(size_t)dst * 64 + lane];
        acc.x += v * p.x;
        acc.y += v * p.y;
    }
    float2 o;
    o.x = acc.x > 0.f ? acc.x : 0.f;
    o.y = acc.y > 0.f ? acc.y : 0.f;
    ((float2*)h)[(size_t)node * 64 + lane] = o;
}

// ---------------- GEMM2: pre2[50000,32] = h[50000,128] @ W2[128,32] ----------------

__global__ __launch_bounds__(256) void gemm2_k(const float* __restrict__ h,
                                               const float* __restrict__ W2,
                                               float* __restrict__ pre2) {
    __shared__ float hs[32][132];        // pad: bank-conflict-free a-reads
    __shared__ float w2s[HIDDEN][N_CLASSES];
    const int t = threadIdx.x;
    const int row0 = blockIdx.x * 32;
#pragma unroll
    for (int j = 0; j < 4; ++j) {        // W2: 1024 float4
        int f = j * 256 + t;
        int r = f >> 3;
        int c = (f & 7) << 2;
        *(float4*)&w2s[r][c] = *(const float4*)(W2 + (size_t)r * N_CLASSES + c);
    }
#pragma unroll
    for (int j = 0; j < 4; ++j) {        // h tile: 32x128 = 1024 float4
        int f = j * 256 + t;
        int r = f >> 5;
        int c = (f & 31) << 2;
        int grr = row0 + r;
        if (grr >= N_NODES) grr = N_NODES - 1;
        *(float4*)&hs[r][c] = *(const float4*)(h + (size_t)grr * HIDDEN + c);
    }
    __syncthreads();
    const int r = t >> 3;
    const int c = (t & 7) << 2;
    float4 acc; acc.x = acc.y = acc.z = acc.w = 0.f;
#pragma unroll 16
    for (int kk = 0; kk < HIDDEN; ++kk) {
        float a = hs[r][kk];
        float4 b = *(const float4*)&w2s[kk][c];
        acc.x += a * b.x; acc.y += a * b.y; acc.z += a * b.z; acc.w += a * b.w;
    }
    int grr = row0 + r;
    if (grr < N_NODES) *(float4*)(pre2 + (size_t)grr * N_CLASSES + c) = acc;
}

// ---------------- SpMM2: out = A @ pre2, one wave per node, 32 feats, 2 edges/iter ----------------

__global__ __launch_bounds__(256) void spmm2_k(const int* __restrict__ rp, const int* __restrict__ cd,
                                               const float* __restrict__ cv, const float* __restrict__ pre2,
                                               float* __restrict__ out) {
    const int g = threadIdx.x >> 6;
    const int lane = threadIdx.x & 63;
    const int node = blockIdx.x * 4 + g;
    if (node >= N_NODES) return;
    const int s = rp[node], e = rp[node + 1];
    const int f = lane & 31;
    const int par = lane >> 5;
    float acc = 0.f;
    for (int i = s + par; i < e; i += 2) {
        int dst = cd[i];
        float v = cv[i];
        acc += v * pre2[(size_t)dst * N_CLASSES + f];
    }
    acc += __shfl_xor(acc, 32);
    if (lane < 32) out[(size_t)node * N_CLASSES + lane] = acc;
}

// ---------------- launch ----------------

extern "C" void kernel_launch(void* const* d_in, const int* in_sizes, int n_in,
                              void* d_out, int out_size, void* d_ws, size_t ws_size,
                              hipStream_t stream) {
    const float* x    = (const float*)d_in[0];
    const int* esrc   = (const int*)d_in[1];
    const int* edst   = (const int*)d_in[2];
    const float* ev   = (const float*)d_in[3];
    const float* W1   = (const float*)d_in[4];
    const float* W2   = (const float*)d_in[5];
    float* out        = (float*)d_out;

    // workspace layout (f32 elems); pre2 aliases pre1 (pre1 dead after spmm1)
    float* pre1   = (float*)d_ws;              // 6,400,000
    float* h      = pre1 + 6400000;            // 6,400,000
    float* pre2   = pre1;                      // 1,600,000 (alias)
    float* csr_val = h + 6400000;              // 800,000
    int* csr_dst  = (int*)(csr_val + 800000);  // 800,000
    int* row_ptr  = csr_dst + 800000;          // 50,001
    int* cursor   = row_ptr + 50048;           // 50,000
    int* bsum     = cursor + 50048;            // 256
    int* boff     = bsum + 256;                // 256

    hipMemsetAsync(cursor, 0, N_NODES * sizeof(int), stream);

    hipLaunchKernelGGL(hist_k,    dim3(3125), dim3(256), 0, stream, esrc, cursor);
    hipLaunchKernelGGL(scan_a,    dim3(196),  dim3(256), 0, stream, cursor, bsum);
    hipLaunchKernelGGL(scan_b,    dim3(1),    dim3(256), 0, stream, bsum, boff);
    hipLaunchKernelGGL(scan_c,    dim3(196),  dim3(256), 0, stream, cursor, boff, row_ptr, cursor);
    hipLaunchKernelGGL(scatter_k, dim3(3125), dim3(256), 0, stream, esrc, edst, ev, cursor, csr_dst, csr_val);

    hipLaunchKernelGGL(gemm1_k,   dim3(782),  dim3(256), 0, stream, x, W1, pre1);
    hipLaunchKernelGGL(spmm1_k,   dim3(12500),dim3(256), 0, stream, row_ptr, csr_dst, csr_val, pre1, h);
    hipLaunchKernelGGL(gemm2_k,   dim3(1563), dim3(256), 0, stream, h, W2, pre2);
    hipLaunchKernelGGL(spmm2_k,   dim3(12500),dim3(256), 0, stream, row_ptr, csr_dst, csr_val, pre2, out);
}

// Round 2
// 256.148 us; speedup vs baseline: 1.4370x; 1.4370x over previous
//
#include <hip/hip_runtime.h>
#include <hip/hip_bf16.h>

#define N_NODES 50000
#define N_EDGES 800000
#define N_FEAT 512
#define HIDDEN 128
#define N_CLASSES 32

typedef __attribute__((ext_vector_type(8))) short bf16x8;
typedef __attribute__((ext_vector_type(4))) float f32x4;

// round-to-nearest-even f32 -> bf16 bits
static __device__ __forceinline__ unsigned short f2bf(float f) {
    unsigned u = __float_as_uint(f);
    u += 0x7FFFu + ((u >> 16) & 1u);
    return (unsigned short)(u >> 16);
}
static __device__ __forceinline__ float bf2f(unsigned short b) {
    return __uint_as_float(((unsigned)b) << 16);
}

// ---------------- CSR build ----------------

__global__ __launch_bounds__(256) void hist_k(const int* __restrict__ src, int* __restrict__ cnt) {
    int i = blockIdx.x * 256 + threadIdx.x;
    if (i < N_EDGES) atomicAdd(&cnt[src[i]], 1);
}

__global__ __launch_bounds__(256) void scan_a(const int* __restrict__ cnt, int* __restrict__ bsum) {
    __shared__ int sd[256];
    int t = threadIdx.x;
    int i = blockIdx.x * 256 + t;
    sd[t] = (i < N_NODES) ? cnt[i] : 0;
    __syncthreads();
    for (int off = 128; off > 0; off >>= 1) {
        if (t < off) sd[t] += sd[t + off];
        __syncthreads();
    }
    if (t == 0) bsum[blockIdx.x] = sd[0];
}

__global__ __launch_bounds__(256) void scan_b(const int* __restrict__ bsum, int* __restrict__ boff) {
    __shared__ int sd[256];
    int t = threadIdx.x;
    int v = (t < 196) ? bsum[t] : 0;
    sd[t] = v;
    __syncthreads();
    for (int off = 1; off < 256; off <<= 1) {
        int xv = (t >= off) ? sd[t - off] : 0;
        __syncthreads();
        sd[t] += xv;
        __syncthreads();
    }
    if (t < 196) boff[t] = sd[t] - v;   // exclusive
}

// cnt may alias cursor — no __restrict__
__global__ __launch_bounds__(256) void scan_c(const int* cnt, const int* boff,
                                              int* row_ptr, int* cursor) {
    __shared__ int sd[256];
    int t = threadIdx.x;
    int i = blockIdx.x * 256 + t;
    int v = (i < N_NODES) ? cnt[i] : 0;
    sd[t] = v;
    __syncthreads();
    for (int off = 1; off < 256; off <<= 1) {
        int xv = (t >= off) ? sd[t - off] : 0;
        __syncthreads();
        sd[t] += xv;
        __syncthreads();
    }
    int start = boff[blockIdx.x] + (sd[t] - v);
    if (i < N_NODES) { row_ptr[i] = start; cursor[i] = start; }
    if (i == N_NODES) row_ptr[N_NODES] = N_EDGES;
}

__global__ __launch_bounds__(256) void scatter_k(const int* __restrict__ src, const int* __restrict__ dst,
                                                 const float* __restrict__ val, int* __restrict__ cursor,
                                                 int* __restrict__ csr_dst, float* __restrict__ csr_val) {
    int i = blockIdx.x * 256 + threadIdx.x;
    if (i >= N_EDGES) return;
    int s = src[i];
    int pos = atomicAdd(&cursor[s], 1);
    csr_dst[pos] = dst[i];
    csr_val[pos] = val[i];
}

// ---------------- W1 transpose + bf16 hi/lo split: W1[512][128] -> W1t_{h,l}[128][512] ----------------

__global__ __launch_bounds__(256) void w1split_k(const float* __restrict__ W1,
                                                 unsigned short* __restrict__ W1t_h,
                                                 unsigned short* __restrict__ W1t_l) {
    int id = blockIdx.x * 256 + threadIdx.x;   // 65536
    int c = id >> 9;          // 0..127
    int k = id & 511;         // 0..511
    float v = W1[(size_t)k * HIDDEN + c];
    unsigned short h = f2bf(v);
    W1t_h[(size_t)c * N_FEAT + k] = h;
    W1t_l[(size_t)c * N_FEAT + k] = f2bf(v - bf2f(h));
}

// ---------------- GEMM1 via MFMA split-bf16: pre1 = x @ W1 ----------------
// 128x128 tile, 4 waves (2x2), wave = 64x64 = 4x4 fragments of 16x16, BK=64.
// acc += Ah*Bh + Ah*Bl + Al*Bh  (Al*Bl ~ 2^-18 rel, dropped)

#define LDT 72   // shorts per LDS row (64 + 8 pad -> 144B stride, 2-way conflicts = free)

__global__ __launch_bounds__(256, 2) void gemm1_mfma(const float* __restrict__ x,
                                                     const unsigned short* __restrict__ W1t_h,
                                                     const unsigned short* __restrict__ W1t_l,
                                                     float* __restrict__ pre1) {
    __shared__ short lds[4 * 128 * LDT];       // Ah, Al, Bh, Bl : 72 KB
    short* Ah = lds;
    short* Al = lds + 128 * LDT;
    short* Bh = lds + 2 * 128 * LDT;
    short* Bl = lds + 3 * 128 * LDT;

    const int t = threadIdx.x;
    const int w = t >> 6;
    const int l = t & 63;
    const int wr = w >> 1;       // 0..1
    const int wc = w & 1;        // 0..1
    const int row0 = blockIdx.x * 128;

    f32x4 acc[4][4];
#pragma unroll
    for (int m = 0; m < 4; ++m)
#pragma unroll
        for (int n = 0; n < 4; ++n) acc[m][n] = (f32x4){0.f, 0.f, 0.f, 0.f};

    const int l15 = l & 15;
    const int lhi = l >> 4;

    for (int k0 = 0; k0 < N_FEAT; k0 += 64) {
        __syncthreads();
        // stage x tile 128x64 f32 -> Ah/Al bf16 (8 float4 per thread)
#pragma unroll
        for (int j = 0; j < 8; ++j) {
            int f = j * 256 + t;
            int ar = f >> 4;              // 0..127
            int ak = (f & 15) << 2;       // 0..60
            int gr = row0 + ar;
            if (gr > N_NODES - 1) gr = N_NODES - 1;
            float4 v = *(const float4*)(x + (size_t)gr * N_FEAT + k0 + ak);
            ushort4 h, lo;
            h.x = f2bf(v.x); lo.x = f2bf(v.x - bf2f(h.x));
            h.y = f2bf(v.y); lo.y = f2bf(v.y - bf2f(h.y));
            h.z = f2bf(v.z); lo.z = f2bf(v.z - bf2f(h.z));
            h.w = f2bf(v.w); lo.w = f2bf(v.w - bf2f(h.w));
            *(ushort4*)&Ah[ar * LDT + ak] = h;
            *(ushort4*)&Al[ar * LDT + ak] = lo;
        }
        // stage W1t tile 128x64 bf16 hi+lo (4 x 16B per thread each)
#pragma unroll
        for (int j = 0; j < 4; ++j) {
            int f = j * 256 + t;
            int br = f >> 3;              // 0..127 (col index)
            int bk = (f & 7) << 3;        // 0..56 shorts
            *(bf16x8*)&Bh[br * LDT + bk] = *(const bf16x8*)(W1t_h + (size_t)br * N_FEAT + k0 + bk);
            *(bf16x8*)&Bl[br * LDT + bk] = *(const bf16x8*)(W1t_l + (size_t)br * N_FEAT + k0 + bk);
        }
        __syncthreads();
#pragma unroll
        for (int ks = 0; ks < 2; ++ks) {
            const int koff = ks * 32 + lhi * 8;
            bf16x8 ah[4], al[4], bh[4], bl[4];
#pragma unroll
            for (int m = 0; m < 4; ++m) {
                int r = wr * 64 + m * 16 + l15;
                ah[m] = *(bf16x8*)&Ah[r * LDT + koff];
                al[m] = *(bf16x8*)&Al[r * LDT + koff];
            }
#pragma unroll
            for (int n = 0; n < 4; ++n) {
                int c = wc * 64 + n * 16 + l15;
                bh[n] = *(bf16x8*)&Bh[c * LDT + koff];
                bl[n] = *(bf16x8*)&Bl[c * LDT + koff];
            }
#pragma unroll
            for (int m = 0; m < 4; ++m)
#pragma unroll
                for (int n = 0; n < 4; ++n) {
                    acc[m][n] = __builtin_amdgcn_mfma_f32_16x16x32_bf16(ah[m], bh[n], acc[m][n], 0, 0, 0);
                    acc[m][n] = __builtin_amdgcn_mfma_f32_16x16x32_bf16(ah[m], bl[n], acc[m][n], 0, 0, 0);
                    acc[m][n] = __builtin_amdgcn_mfma_f32_16x16x32_bf16(al[m], bh[n], acc[m][n], 0, 0, 0);
                }
        }
    }
    // epilogue: C/D layout col=lane&15, row=(lane>>4)*4+reg
    const int r0 = row0 + wr * 64;
    const int c0 = wc * 64;
#pragma unroll
    for (int m = 0; m < 4; ++m)
#pragma unroll
        for (int n = 0; n < 4; ++n) {
#pragma unroll
            for (int j = 0; j < 4; ++j) {
                int r = r0 + m * 16 + lhi * 4 + j;
                if (r < N_NODES) pre1[(size_t)r * HIDDEN + c0 + n * 16 + l15] = acc[m][n][j];
            }
        }
}

// ---------------- SpMM1: h = relu(A @ pre1), one wave per node, float2/lane, 2-edge unroll ----------------

__global__ __launch_bounds__(256) void spmm1_k(const int* __restrict__ rp, const int* __restrict__ cd,
                                               const float* __restrict__ cv, const float* __restrict__ pre1,
                                               float* __restrict__ h) {
    const int g = threadIdx.x >> 6;
    const int lane = threadIdx.x & 63;
    const int node = blockIdx.x * 4 + g;
    if (node >= N_NODES) return;
    const int s = rp[node], e = rp[node + 1];
    const float2* __restrict__ P = (const float2*)pre1;
    float2 a0; a0.x = 0.f; a0.y = 0.f;
    float2 a1; a1.x = 0.f; a1.y = 0.f;
    int i = s;
    for (; i + 2 <= e; i += 2) {
        int d0 = cd[i], d1 = cd[i + 1];
        float v0 = cv[i], v1 = cv[i + 1];
        float2 p0 = P[(size_t)d0 * 64 + lane];
        float2 p1 = P[(size_t)d1 * 64 + lane];
        a0.x += v0 * p0.x; a0.y += v0 * p0.y;
        a1.x += v1 * p1.x; a1.y += v1 * p1.y;
    }
    if (i < e) {
        int d0 = cd[i];
        float v0 = cv[i];
        float2 p0 = P[(size_t)d0 * 64 + lane];
        a0.x += v0 * p0.x; a0.y += v0 * p0.y;
    }
    a0.x += a1.x; a0.y += a1.y;
    float2 o;
    o.x = a0.x > 0.f ? a0.x : 0.f;
    o.y = a0.y > 0.f ? a0.y : 0.f;
    ((float2*)h)[(size_t)node * 64 + lane] = o;
}

// ---------------- GEMM2: pre2[50000,32] = h[50000,128] @ W2[128,32] ----------------

__global__ __launch_bounds__(256) void gemm2_k(const float* __restrict__ h,
                                               const float* __restrict__ W2,
                                               float* __restrict__ pre2) {
    __shared__ float hs[32][132];
    __shared__ float w2s[HIDDEN][N_CLASSES];
    const int t = threadIdx.x;
    const int row0 = blockIdx.x * 32;
#pragma unroll
    for (int j = 0; j < 4; ++j) {
        int f = j * 256 + t;
        int r = f >> 3;
        int c = (f & 7) << 2;
        *(float4*)&w2s[r][c] = *(const float4*)(W2 + (size_t)r * N_CLASSES + c);
    }
#pragma unroll
    for (int j = 0; j < 4; ++j) {
        int f = j * 256 + t;
        int r = f >> 5;
        int c = (f & 31) << 2;
        int grr = row0 + r;
        if (grr >= N_NODES) grr = N_NODES - 1;
        *(float4*)&hs[r][c] = *(const float4*)(h + (size_t)grr * HIDDEN + c);
    }
    __syncthreads();
    const int r = t >> 3;
    const int c = (t & 7) << 2;
    float4 acc; acc.x = acc.y = acc.z = acc.w = 0.f;
#pragma unroll 16
    for (int kk = 0; kk < HIDDEN; ++kk) {
        float a = hs[r][kk];
        float4 b = *(const float4*)&w2s[kk][c];
        acc.x += a * b.x; acc.y += a * b.y; acc.z += a * b.z; acc.w += a * b.w;
    }
    int grr = row0 + r;
    if (grr < N_NODES) *(float4*)(pre2 + (size_t)grr * N_CLASSES + c) = acc;
}

// ---------------- SpMM2: out = A @ pre2 ----------------

__global__ __launch_bounds__(256) void spmm2_k(const int* __restrict__ rp, const int* __restrict__ cd,
                                               const float* __restrict__ cv, const float* __restrict__ pre2,
                                               float* __restrict__ out) {
    const int g = threadIdx.x >> 6;
    const int lane = threadIdx.x & 63;
    const int node = blockIdx.x * 4 + g;
    if (node >= N_NODES) return;
    const int s = rp[node], e = rp[node + 1];
    const int f = lane & 31;
    const int par = lane >> 5;
    float acc = 0.f;
    for (int i = s + par; i < e; i += 2) {
        int dst = cd[i];
        float v = cv[i];
        acc += v * pre2[(size_t)dst * N_CLASSES + f];
    }
    acc += __shfl_xor(acc, 32);
    if (lane < 32) out[(size_t)node * N_CLASSES + lane] = acc;
}

// ---------------- launch ----------------

extern "C" void kernel_launch(void* const* d_in, const int* in_sizes, int n_in,
                              void* d_out, int out_size, void* d_ws, size_t ws_size,
                              hipStream_t stream) {
    const float* x    = (const float*)d_in[0];
    const int* esrc   = (const int*)d_in[1];
    const int* edst   = (const int*)d_in[2];
    const float* ev   = (const float*)d_in[3];
    const float* W1   = (const float*)d_in[4];
    const float* W2   = (const float*)d_in[5];
    float* out        = (float*)d_out;

    // workspace layout (f32 elems); pre2 aliases pre1 (pre1 dead after spmm1)
    float* pre1   = (float*)d_ws;              // 6,400,000
    float* h      = pre1 + 6400000;            // 6,400,000
    float* pre2   = pre1;                      // 1,600,000 (alias)
    float* csr_val = h + 6400000;              // 800,000
    int* csr_dst  = (int*)(csr_val + 800000);  // 800,000
    int* row_ptr  = csr_dst + 800000;          // 50,001
    int* cursor   = row_ptr + 50048;           // 50,000
    int* bsum     = cursor + 50048;            // 256
    int* boff     = bsum + 256;                // 256
    unsigned short* W1t_h = (unsigned short*)(boff + 256);   // 65,536 shorts
    unsigned short* W1t_l = W1t_h + 65536;                   // 65,536 shorts

    hipMemsetAsync(cursor, 0, N_NODES * sizeof(int), stream);

    hipLaunchKernelGGL(hist_k,     dim3(3125), dim3(256), 0, stream, esrc, cursor);
    hipLaunchKernelGGL(w1split_k,  dim3(256),  dim3(256), 0, stream, W1, W1t_h, W1t_l);
    hipLaunchKernelGGL(scan_a,     dim3(196),  dim3(256), 0, stream, cursor, bsum);
    hipLaunchKernelGGL(scan_b,     dim3(1),    dim3(256), 0, stream, bsum, boff);
    hipLaunchKernelGGL(scan_c,     dim3(196),  dim3(256), 0, stream, cursor, boff, row_ptr, cursor);
    hipLaunchKernelGGL(scatter_k,  dim3(3125), dim3(256), 0, stream, esrc, edst, ev, cursor, csr_dst, csr_val);

    hipLaunchKernelGGL(gemm1_mfma, dim3(391),  dim3(256), 0, stream, x, W1t_h, W1t_l, pre1);
    hipLaunchKernelGGL(spmm1_k,    dim3(12500),dim3(256), 0, stream, row_ptr, csr_dst, csr_val, pre1, h);
    hipLaunchKernelGGL(gemm2_k,    dim3(1563), dim3(256), 0, stream, h, W2, pre2);
    hipLaunchKernelGGL(spmm2_k,    dim3(12500),dim3(256), 0, stream, row_ptr, csr_dst, csr_val, pre2, out);
}

// Round 3
// 231.973 us; speedup vs baseline: 1.5868x; 1.1042x over previous
//
#include <hip/hip_runtime.h>
#include <hip/hip_bf16.h>

#define N_NODES 50000
#define N_EDGES 800000
#define N_FEAT 512
#define HIDDEN 128
#define N_CLASSES 32

typedef __attribute__((ext_vector_type(8))) short bf16x8;
typedef __attribute__((ext_vector_type(4))) float f32x4;

// round-to-nearest-even f32 -> bf16 bits
static __device__ __forceinline__ unsigned short f2bf(float f) {
    unsigned u = __float_as_uint(f);
    u += 0x7FFFu + ((u >> 16) & 1u);
    return (unsigned short)(u >> 16);
}
static __device__ __forceinline__ float bf2f(unsigned short b) {
    return __uint_as_float(((unsigned)b) << 16);
}
// unpack uint = (bf16_hi<<16)|bf16_lo
static __device__ __forceinline__ float bflo(unsigned u) { return __uint_as_float(u << 16); }
static __device__ __forceinline__ float bfhi(unsigned u) { return __uint_as_float(u & 0xFFFF0000u); }
static __device__ __forceinline__ unsigned pack2(float a, float b) {
    return (unsigned)f2bf(a) | ((unsigned)f2bf(b) << 16);
}

// ---------------- CSR build ----------------

__global__ __launch_bounds__(256) void hist_k(const int* __restrict__ src, int* __restrict__ cnt) {
    int i = blockIdx.x * 256 + threadIdx.x;
    if (i < N_EDGES) atomicAdd(&cnt[src[i]], 1);
}

__global__ __launch_bounds__(256) void scan_a(const int* __restrict__ cnt, int* __restrict__ bsum) {
    __shared__ int sd[256];
    int t = threadIdx.x;
    int i = blockIdx.x * 256 + t;
    sd[t] = (i < N_NODES) ? cnt[i] : 0;
    __syncthreads();
    for (int off = 128; off > 0; off >>= 1) {
        if (t < off) sd[t] += sd[t + off];
        __syncthreads();
    }
    if (t == 0) bsum[blockIdx.x] = sd[0];
}

__global__ __launch_bounds__(256) void scan_b(const int* __restrict__ bsum, int* __restrict__ boff) {
    __shared__ int sd[256];
    int t = threadIdx.x;
    int v = (t < 196) ? bsum[t] : 0;
    sd[t] = v;
    __syncthreads();
    for (int off = 1; off < 256; off <<= 1) {
        int xv = (t >= off) ? sd[t - off] : 0;
        __syncthreads();
        sd[t] += xv;
        __syncthreads();
    }
    if (t < 196) boff[t] = sd[t] - v;   // exclusive
}

// cnt may alias cursor — no __restrict__
__global__ __launch_bounds__(256) void scan_c(const int* cnt, const int* boff,
                                              int* row_ptr, int* cursor) {
    __shared__ int sd[256];
    int t = threadIdx.x;
    int i = blockIdx.x * 256 + t;
    int v = (i < N_NODES) ? cnt[i] : 0;
    sd[t] = v;
    __syncthreads();
    for (int off = 1; off < 256; off <<= 1) {
        int xv = (t >= off) ? sd[t - off] : 0;
        __syncthreads();
        sd[t] += xv;
        __syncthreads();
    }
    int start = boff[blockIdx.x] + (sd[t] - v);
    if (i < N_NODES) { row_ptr[i] = start; cursor[i] = start; }
    if (i == N_NODES) row_ptr[N_NODES] = N_EDGES;
}

__global__ __launch_bounds__(256) void scatter_k(const int* __restrict__ src, const int* __restrict__ dst,
                                                 const float* __restrict__ val, int* __restrict__ cursor,
                                                 int* __restrict__ csr_dst, float* __restrict__ csr_val) {
    int i = blockIdx.x * 256 + threadIdx.x;
    if (i >= N_EDGES) return;
    int s = src[i];
    int pos = atomicAdd(&cursor[s], 1);
    csr_dst[pos] = dst[i];
    csr_val[pos] = val[i];
}

// ---------------- W1 transpose + bf16: W1[512][128] -> W1t[128][512] bf16 ----------------

__global__ __launch_bounds__(256) void w1conv_k(const float* __restrict__ W1,
                                                unsigned short* __restrict__ W1t) {
    int id = blockIdx.x * 256 + threadIdx.x;   // 65536
    int c = id >> 9;          // 0..127
    int k = id & 511;         // 0..511
    W1t[(size_t)c * N_FEAT + k] = f2bf(W1[(size_t)k * HIDDEN + c]);
}

// ---------------- GEMM1 via bf16 MFMA: pre1b = bf16(x @ W1) ----------------
// 128x128 tile, 4 waves (2x2), wave = 64x64 = 4x4 fragments of 16x16, BK=64.

#define LDT 72   // shorts per LDS row (64 + 8 pad -> 144B stride, 2-way conflicts = free)

__global__ __launch_bounds__(256, 3) void gemm1_mfma(const float* __restrict__ x,
                                                     const unsigned short* __restrict__ W1t,
                                                     unsigned short* __restrict__ pre1b) {
    __shared__ short As[128 * LDT];
    __shared__ short Bs[128 * LDT];

    const int t = threadIdx.x;
    const int w = t >> 6;
    const int l = t & 63;
    const int wr = w >> 1;       // 0..1
    const int wc = w & 1;        // 0..1
    const int row0 = blockIdx.x * 128;

    f32x4 acc[4][4];
#pragma unroll
    for (int m = 0; m < 4; ++m)
#pragma unroll
        for (int n = 0; n < 4; ++n) acc[m][n] = (f32x4){0.f, 0.f, 0.f, 0.f};

    const int l15 = l & 15;
    const int lhi = l >> 4;

    for (int k0 = 0; k0 < N_FEAT; k0 += 64) {
        __syncthreads();
        // stage x tile 128x64 f32 -> bf16 (8 float4 per thread)
#pragma unroll
        for (int j = 0; j < 8; ++j) {
            int f = j * 256 + t;
            int ar = f >> 4;              // 0..127
            int ak = (f & 15) << 2;       // 0..60
            int gr = row0 + ar;
            if (gr > N_NODES - 1) gr = N_NODES - 1;
            float4 v = *(const float4*)(x + (size_t)gr * N_FEAT + k0 + ak);
            ushort4 hh;
            hh.x = f2bf(v.x); hh.y = f2bf(v.y); hh.z = f2bf(v.z); hh.w = f2bf(v.w);
            *(ushort4*)&As[ar * LDT + ak] = hh;
        }
        // stage W1t tile 128x64 bf16 (4 x 16B per thread)
#pragma unroll
        for (int j = 0; j < 4; ++j) {
            int f = j * 256 + t;
            int br = f >> 3;              // 0..127 (col index)
            int bk = (f & 7) << 3;        // 0..56 shorts
            *(bf16x8*)&Bs[br * LDT + bk] = *(const bf16x8*)(W1t + (size_t)br * N_FEAT + k0 + bk);
        }
        __syncthreads();
#pragma unroll
        for (int ks = 0; ks < 2; ++ks) {
            const int koff = ks * 32 + lhi * 8;
            bf16x8 ah[4], bh[4];
#pragma unroll
            for (int m = 0; m < 4; ++m)
                ah[m] = *(bf16x8*)&As[(wr * 64 + m * 16 + l15) * LDT + koff];
#pragma unroll
            for (int n = 0; n < 4; ++n)
                bh[n] = *(bf16x8*)&Bs[(wc * 64 + n * 16 + l15) * LDT + koff];
#pragma unroll
            for (int m = 0; m < 4; ++m)
#pragma unroll
                for (int n = 0; n < 4; ++n)
                    acc[m][n] = __builtin_amdgcn_mfma_f32_16x16x32_bf16(ah[m], bh[n], acc[m][n], 0, 0, 0);
        }
    }
    // epilogue: C/D layout col=lane&15, row=(lane>>4)*4+reg ; write bf16
    const int r0 = row0 + wr * 64;
    const int c0 = wc * 64;
#pragma unroll
    for (int m = 0; m < 4; ++m)
#pragma unroll
        for (int n = 0; n < 4; ++n) {
#pragma unroll
            for (int j = 0; j < 4; ++j) {
                int r = r0 + m * 16 + lhi * 4 + j;
                if (r < N_NODES) pre1b[(size_t)r * HIDDEN + c0 + n * 16 + l15] = f2bf(acc[m][n][j]);
            }
        }
}

// ---------------- SpMM1: hb = bf16(relu(A @ pre1)), one wave per node, 1 uint (2 feats)/lane ----------------

__global__ __launch_bounds__(256) void spmm1_k(const int* __restrict__ rp, const int* __restrict__ cd,
                                               const float* __restrict__ cv, const unsigned* __restrict__ P,
                                               unsigned* __restrict__ hb) {
    const int g = threadIdx.x >> 6;
    const int lane = threadIdx.x & 63;
    const int node = blockIdx.x * 4 + g;
    if (node >= N_NODES) return;
    const int s = rp[node], e = rp[node + 1];
    float2 a0; a0.x = 0.f; a0.y = 0.f;
    float2 a1; a1.x = 0.f; a1.y = 0.f;
    int i = s;
    for (; i + 2 <= e; i += 2) {
        int d0 = cd[i], d1 = cd[i + 1];
        float v0 = cv[i], v1 = cv[i + 1];
        unsigned u0 = P[(size_t)d0 * 64 + lane];
        unsigned u1 = P[(size_t)d1 * 64 + lane];
        a0.x += v0 * bflo(u0); a0.y += v0 * bfhi(u0);
        a1.x += v1 * bflo(u1); a1.y += v1 * bfhi(u1);
    }
    if (i < e) {
        int d0 = cd[i];
        float v0 = cv[i];
        unsigned u0 = P[(size_t)d0 * 64 + lane];
        a0.x += v0 * bflo(u0); a0.y += v0 * bfhi(u0);
    }
    a0.x += a1.x; a0.y += a1.y;
    a0.x = a0.x > 0.f ? a0.x : 0.f;
    a0.y = a0.y > 0.f ? a0.y : 0.f;
    hb[(size_t)node * 64 + lane] = pack2(a0.x, a0.y);
}

// ---------------- GEMM2: pre2b[50000,32] = bf16(h @ W2) ----------------

__global__ __launch_bounds__(256) void gemm2_k(const unsigned* __restrict__ hb,
                                               const float* __restrict__ W2,
                                               unsigned short* __restrict__ pre2b) {
    __shared__ float hs[32][132];
    __shared__ float w2s[HIDDEN][N_CLASSES];
    const int t = threadIdx.x;
    const int row0 = blockIdx.x * 32;
#pragma unroll
    for (int j = 0; j < 4; ++j) {        // W2: 1024 float4
        int f = j * 256 + t;
        int r = f >> 3;
        int c = (f & 7) << 2;
        *(float4*)&w2s[r][c] = *(const float4*)(W2 + (size_t)r * N_CLASSES + c);
    }
#pragma unroll
    for (int j = 0; j < 2; ++j) {        // h tile: 32 rows x 64 uints = 2048 uints
        int f = j * 256 + t;
        int r = f >> 4;                  // 0..31
        int cu = (f & 15) << 2;          // uint col 0..60 step 4
        int grr = row0 + r;
        if (grr >= N_NODES) grr = N_NODES - 1;
        uint4 u = *(const uint4*)(hb + (size_t)grr * 64 + cu);
        hs[r][2 * cu + 0] = bflo(u.x); hs[r][2 * cu + 1] = bfhi(u.x);
        hs[r][2 * cu + 2] = bflo(u.y); hs[r][2 * cu + 3] = bfhi(u.y);
        hs[r][2 * cu + 4] = bflo(u.z); hs[r][2 * cu + 5] = bfhi(u.z);
        hs[r][2 * cu + 6] = bflo(u.w); hs[r][2 * cu + 7] = bfhi(u.w);
    }
    __syncthreads();
    const int r = t >> 3;
    const int c = (t & 7) << 2;
    float4 acc; acc.x = acc.y = acc.z = acc.w = 0.f;
#pragma unroll 16
    for (int kk = 0; kk < HIDDEN; ++kk) {
        float a = hs[r][kk];
        float4 b = *(const float4*)&w2s[kk][c];
        acc.x += a * b.x; acc.y += a * b.y; acc.z += a * b.z; acc.w += a * b.w;
    }
    int grr = row0 + r;
    if (grr < N_NODES) {
        uint2 o;
        o.x = pack2(acc.x, acc.y);
        o.y = pack2(acc.z, acc.w);
        *(uint2*)&pre2b[(size_t)grr * N_CLASSES + c] = o;
    }
}

// ---------------- SpMM2: out = A @ pre2 ; 16 lanes/edge, 4 edges/iter ----------------

__global__ __launch_bounds__(256) void spmm2_k(const int* __restrict__ rp, const int* __restrict__ cd,
                                               const float* __restrict__ cv, const unsigned* __restrict__ P2,
                                               float* __restrict__ out) {
    const int g = threadIdx.x >> 6;
    const int lane = threadIdx.x & 63;
    const int node = blockIdx.x * 4 + g;
    if (node >= N_NODES) return;
    const int s = rp[node], e = rp[node + 1];
    const int f2 = lane & 15;      // uint index: feats 2*f2, 2*f2+1
    const int par = lane >> 4;     // 0..3
    float ax = 0.f, ay = 0.f;
    for (int i = s + par; i < e; i += 4) {
        int dst = cd[i];
        float v = cv[i];
        unsigned u = P2[(size_t)dst * 16 + f2];
        ax += v * bflo(u);
        ay += v * bfhi(u);
    }
    ax += __shfl_xor(ax, 16); ay += __shfl_xor(ay, 16);
    ax += __shfl_xor(ax, 32); ay += __shfl_xor(ay, 32);
    if (lane < 16) {
        float2 o; o.x = ax; o.y = ay;
        ((float2*)out)[(size_t)node * 16 + f2] = o;
    }
}

// ---------------- launch ----------------

extern "C" void kernel_launch(void* const* d_in, const int* in_sizes, int n_in,
                              void* d_out, int out_size, void* d_ws, size_t ws_size,
                              hipStream_t stream) {
    const float* x    = (const float*)d_in[0];
    const int* esrc   = (const int*)d_in[1];
    const int* edst   = (const int*)d_in[2];
    const float* ev   = (const float*)d_in[3];
    const float* W1   = (const float*)d_in[4];
    const float* W2   = (const float*)d_in[5];
    float* out        = (float*)d_out;

    // workspace layout; pre2b aliases pre1b (pre1b dead after spmm1)
    unsigned short* pre1b = (unsigned short*)d_ws;            // 6,400,000 ushort (12.8 MB)
    unsigned* hb          = (unsigned*)(pre1b + 6400000);     // 3,200,000 uint (12.8 MB)
    unsigned short* pre2b = pre1b;                            // 1,600,000 ushort (alias)
    float* csr_val        = (float*)(hb + 3200000);           // 800,000
    int* csr_dst          = (int*)(csr_val + 800000);         // 800,000
    int* row_ptr          = csr_dst + 800000;                 // 50,001 (pad 50,048)
    int* cursor           = row_ptr + 50048;
    int* bsum             = cursor + 50048;
    int* boff             = bsum + 256;
    unsigned short* W1t   = (unsigned short*)(boff + 256);    // 65,536 ushort

    hipMemsetAsync(cursor, 0, N_NODES * sizeof(int), stream);

    hipLaunchKernelGGL(hist_k,     dim3(3125), dim3(256), 0, stream, esrc, cursor);
    hipLaunchKernelGGL(w1conv_k,   dim3(256),  dim3(256), 0, stream, W1, W1t);
    hipLaunchKernelGGL(scan_a,     dim3(196),  dim3(256), 0, stream, cursor, bsum);
    hipLaunchKernelGGL(scan_b,     dim3(1),    dim3(256), 0, stream, bsum, boff);
    hipLaunchKernelGGL(scan_c,     dim3(196),  dim3(256), 0, stream, cursor, boff, row_ptr, cursor);
    hipLaunchKernelGGL(scatter_k,  dim3(3125), dim3(256), 0, stream, esrc, edst, ev, cursor, csr_dst, csr_val);

    hipLaunchKernelGGL(gemm1_mfma, dim3(391),  dim3(256), 0, stream, x, W1t, pre1b);
    hipLaunchKernelGGL(spmm1_k,    dim3(12500),dim3(256), 0, stream, row_ptr, csr_dst, csr_val, (const unsigned*)pre1b, hb);
    hipLaunchKernelGGL(gemm2_k,    dim3(1563), dim3(256), 0, stream, hb, W2, pre2b);
    hipLaunchKernelGGL(spmm2_k,    dim3(12500),dim3(256), 0, stream, row_ptr, csr_dst, csr_val, (const unsigned*)pre2b, out);
}

// Round 4
// 230.648 us; speedup vs baseline: 1.5959x; 1.0057x over previous
//
#include <hip/hip_runtime.h>
#include <hip/hip_bf16.h>

#define N_NODES 50000
#define N_EDGES 800000
#define N_FEAT 512
#define HIDDEN 128
#define N_CLASSES 32

typedef __attribute__((ext_vector_type(8))) short bf16x8;
typedef __attribute__((ext_vector_type(4))) float f32x4;

// round-to-nearest-even f32 -> bf16 bits
static __device__ __forceinline__ unsigned short f2bf(float f) {
    unsigned u = __float_as_uint(f);
    u += 0x7FFFu + ((u >> 16) & 1u);
    return (unsigned short)(u >> 16);
}
static __device__ __forceinline__ float bf2f(unsigned short b) {
    return __uint_as_float(((unsigned)b) << 16);
}
// unpack uint = (bf16_hi<<16)|bf16_lo
static __device__ __forceinline__ float bflo(unsigned u) { return __uint_as_float(u << 16); }
static __device__ __forceinline__ float bfhi(unsigned u) { return __uint_as_float(u & 0xFFFF0000u); }
static __device__ __forceinline__ unsigned pack2(float a, float b) {
    return (unsigned)f2bf(a) | ((unsigned)f2bf(b) << 16);
}

// ---------------- CSR build ----------------

__global__ __launch_bounds__(256) void zero_k(int* __restrict__ p) {
    int i = blockIdx.x * 256 + threadIdx.x;
    if (i < N_NODES) p[i] = 0;
}

__global__ __launch_bounds__(256) void hist_k(const int* __restrict__ src, int* __restrict__ cnt) {
    int i = blockIdx.x * 256 + threadIdx.x;
    if (i < N_EDGES) atomicAdd(&cnt[src[i]], 1);
}

__global__ __launch_bounds__(256) void scan_a(const int* __restrict__ cnt, int* __restrict__ bsum) {
    __shared__ int sd[256];
    int t = threadIdx.x;
    int i = blockIdx.x * 256 + t;
    sd[t] = (i < N_NODES) ? cnt[i] : 0;
    __syncthreads();
    for (int off = 128; off > 0; off >>= 1) {
        if (t < off) sd[t] += sd[t + off];
        __syncthreads();
    }
    if (t == 0) bsum[blockIdx.x] = sd[0];
}

__global__ __launch_bounds__(256) void scan_b(const int* __restrict__ bsum, int* __restrict__ boff) {
    __shared__ int sd[256];
    int t = threadIdx.x;
    int v = (t < 196) ? bsum[t] : 0;
    sd[t] = v;
    __syncthreads();
    for (int off = 1; off < 256; off <<= 1) {
        int xv = (t >= off) ? sd[t - off] : 0;
        __syncthreads();
        sd[t] += xv;
        __syncthreads();
    }
    if (t < 196) boff[t] = sd[t] - v;   // exclusive
}

// cnt may alias cursor — no __restrict__
__global__ __launch_bounds__(256) void scan_c(const int* cnt, const int* boff,
                                              int* row_ptr, int* cursor) {
    __shared__ int sd[256];
    int t = threadIdx.x;
    int i = blockIdx.x * 256 + t;
    int v = (i < N_NODES) ? cnt[i] : 0;
    sd[t] = v;
    __syncthreads();
    for (int off = 1; off < 256; off <<= 1) {
        int xv = (t >= off) ? sd[t - off] : 0;
        __syncthreads();
        sd[t] += xv;
        __syncthreads();
    }
    int start = boff[blockIdx.x] + (sd[t] - v);
    if (i < N_NODES) { row_ptr[i] = start; cursor[i] = start; }
    if (i == N_NODES) row_ptr[N_NODES] = N_EDGES;
}

__global__ __launch_bounds__(256) void scatter_k(const int* __restrict__ src, const int* __restrict__ dst,
                                                 const float* __restrict__ val, int* __restrict__ cursor,
                                                 int* __restrict__ csr_dst, float* __restrict__ csr_val) {
    int i = blockIdx.x * 256 + threadIdx.x;
    if (i >= N_EDGES) return;
    int s = src[i];
    int pos = atomicAdd(&cursor[s], 1);
    csr_dst[pos] = dst[i];
    csr_val[pos] = val[i];
}

// ---------------- W1 transpose + bf16: W1[512][128] -> W1t[128][512] bf16 ----------------

__global__ __launch_bounds__(256) void w1conv_k(const float* __restrict__ W1,
                                                unsigned short* __restrict__ W1t) {
    int id = blockIdx.x * 256 + threadIdx.x;   // 65536
    int c = id >> 9;          // 0..127
    int k = id & 511;         // 0..511
    W1t[(size_t)c * N_FEAT + k] = f2bf(W1[(size_t)k * HIDDEN + c]);
}

// ---------------- GEMM1 via bf16 MFMA: pre1b = bf16(x @ W1) ----------------
// 64x128 tile, grid 782 (~3 blocks/CU), 4 waves: wave w -> cols w*32..w*32+31.
// Per wave: 4x2 fragments of 16x16, BK=64.

#define LDT 72   // shorts per LDS row (64 + 8 pad -> 144B stride, 2-way conflicts = free)

__global__ __launch_bounds__(256, 4) void gemm1_mfma(const float* __restrict__ x,
                                                     const unsigned short* __restrict__ W1t,
                                                     unsigned short* __restrict__ pre1b) {
    __shared__ short As[64 * LDT];     // 9.2 KB
    __shared__ short Bs[128 * LDT];    // 18.4 KB

    const int t = threadIdx.x;
    const int w = t >> 6;        // 0..3: col quarter
    const int l = t & 63;
    const int row0 = blockIdx.x * 64;
    const int l15 = l & 15;
    const int lhi = l >> 4;

    f32x4 acc[4][2];
#pragma unroll
    for (int m = 0; m < 4; ++m)
#pragma unroll
        for (int n = 0; n < 2; ++n) acc[m][n] = (f32x4){0.f, 0.f, 0.f, 0.f};

    for (int k0 = 0; k0 < N_FEAT; k0 += 64) {
        __syncthreads();
        // stage x tile 64x64 f32 -> bf16 (4 float4 per thread)
#pragma unroll
        for (int j = 0; j < 4; ++j) {
            int f = j * 256 + t;
            int ar = f >> 4;              // 0..63
            int ak = (f & 15) << 2;       // 0..60
            int gr = row0 + ar;
            if (gr > N_NODES - 1) gr = N_NODES - 1;
            float4 v = *(const float4*)(x + (size_t)gr * N_FEAT + k0 + ak);
            ushort4 hh;
            hh.x = f2bf(v.x); hh.y = f2bf(v.y); hh.z = f2bf(v.z); hh.w = f2bf(v.w);
            *(ushort4*)&As[ar * LDT + ak] = hh;
        }
        // stage W1t tile 128x64 bf16 (4 x 16B per thread)
#pragma unroll
        for (int j = 0; j < 4; ++j) {
            int f = j * 256 + t;
            int br = f >> 3;              // 0..127 (col index)
            int bk = (f & 7) << 3;        // 0..56 shorts
            *(bf16x8*)&Bs[br * LDT + bk] = *(const bf16x8*)(W1t + (size_t)br * N_FEAT + k0 + bk);
        }
        __syncthreads();
#pragma unroll
        for (int ks = 0; ks < 2; ++ks) {
            const int koff = ks * 32 + lhi * 8;
            bf16x8 af[4], bf[2];
#pragma unroll
            for (int m = 0; m < 4; ++m)
                af[m] = *(bf16x8*)&As[(m * 16 + l15) * LDT + koff];
#pragma unroll
            for (int n = 0; n < 2; ++n)
                bf[n] = *(bf16x8*)&Bs[(w * 32 + n * 16 + l15) * LDT + koff];
#pragma unroll
            for (int m = 0; m < 4; ++m)
#pragma unroll
                for (int n = 0; n < 2; ++n)
                    acc[m][n] = __builtin_amdgcn_mfma_f32_16x16x32_bf16(af[m], bf[n], acc[m][n], 0, 0, 0);
        }
    }
    // epilogue: C/D layout col=lane&15, row=(lane>>4)*4+reg ; write bf16
    const int c0 = w * 32;
#pragma unroll
    for (int m = 0; m < 4; ++m)
#pragma unroll
        for (int n = 0; n < 2; ++n) {
#pragma unroll
            for (int j = 0; j < 4; ++j) {
                int r = row0 + m * 16 + lhi * 4 + j;
                if (r < N_NODES) pre1b[(size_t)r * HIDDEN + c0 + n * 16 + l15] = f2bf(acc[m][n][j]);
            }
        }
}

// ---------------- SpMM1: hb = bf16(relu(A @ pre1)), one wave per node, 1 uint (2 feats)/lane ----------------

__global__ __launch_bounds__(256) void spmm1_k(const int* __restrict__ rp, const int* __restrict__ cd,
                                               const float* __restrict__ cv, const unsigned* __restrict__ P,
                                               unsigned* __restrict__ hb) {
    const int g = threadIdx.x >> 6;
    const int lane = threadIdx.x & 63;
    const int node = blockIdx.x * 4 + g;
    if (node >= N_NODES) return;
    const int s = rp[node], e = rp[node + 1];
    float2 a0; a0.x = 0.f; a0.y = 0.f;
    float2 a1; a1.x = 0.f; a1.y = 0.f;
    int i = s;
    for (; i + 2 <= e; i += 2) {
        int d0 = cd[i], d1 = cd[i + 1];
        float v0 = cv[i], v1 = cv[i + 1];
        unsigned u0 = P[(size_t)d0 * 64 + lane];
        unsigned u1 = P[(size_t)d1 * 64 + lane];
        a0.x += v0 * bflo(u0); a0.y += v0 * bfhi(u0);
        a1.x += v1 * bflo(u1); a1.y += v1 * bfhi(u1);
    }
    if (i < e) {
        int d0 = cd[i];
        float v0 = cv[i];
        unsigned u0 = P[(size_t)d0 * 64 + lane];
        a0.x += v0 * bflo(u0); a0.y += v0 * bfhi(u0);
    }
    a0.x += a1.x; a0.y += a1.y;
    a0.x = a0.x > 0.f ? a0.x : 0.f;
    a0.y = a0.y > 0.f ? a0.y : 0.f;
    hb[(size_t)node * 64 + lane] = pack2(a0.x, a0.y);
}

// ---------------- GEMM2: pre2b[50000,32] = bf16(h @ W2) ----------------

__global__ __launch_bounds__(256) void gemm2_k(const unsigned* __restrict__ hb,
                                               const float* __restrict__ W2,
                                               unsigned short* __restrict__ pre2b) {
    __shared__ float hs[32][132];
    __shared__ float w2s[HIDDEN][N_CLASSES];
    const int t = threadIdx.x;
    const int row0 = blockIdx.x * 32;
#pragma unroll
    for (int j = 0; j < 4; ++j) {        // W2: 1024 float4
        int f = j * 256 + t;
        int r = f >> 3;
        int c = (f & 7) << 2;
        *(float4*)&w2s[r][c] = *(const float4*)(W2 + (size_t)r * N_CLASSES + c);
    }
#pragma unroll
    for (int j = 0; j < 2; ++j) {        // h tile: 32 rows x 64 uints = 2048 uints
        int f = j * 256 + t;
        int r = f >> 4;                  // 0..31
        int cu = (f & 15) << 2;          // uint col 0..60 step 4
        int grr = row0 + r;
        if (grr >= N_NODES) grr = N_NODES - 1;
        uint4 u = *(const uint4*)(hb + (size_t)grr * 64 + cu);
        hs[r][2 * cu + 0] = bflo(u.x); hs[r][2 * cu + 1] = bfhi(u.x);
        hs[r][2 * cu + 2] = bflo(u.y); hs[r][2 * cu + 3] = bfhi(u.y);
        hs[r][2 * cu + 4] = bflo(u.z); hs[r][2 * cu + 5] = bfhi(u.z);
        hs[r][2 * cu + 6] = bflo(u.w); hs[r][2 * cu + 7] = bfhi(u.w);
    }
    __syncthreads();
    const int r = t >> 3;
    const int c = (t & 7) << 2;
    float4 acc; acc.x = acc.y = acc.z = acc.w = 0.f;
#pragma unroll 16
    for (int kk = 0; kk < HIDDEN; ++kk) {
        float a = hs[r][kk];
        float4 b = *(const float4*)&w2s[kk][c];
        acc.x += a * b.x; acc.y += a * b.y; acc.z += a * b.z; acc.w += a * b.w;
    }
    int grr = row0 + r;
    if (grr < N_NODES) {
        uint2 o;
        o.x = pack2(acc.x, acc.y);
        o.y = pack2(acc.z, acc.w);
        *(uint2*)&pre2b[(size_t)grr * N_CLASSES + c] = o;
    }
}

// ---------------- SpMM2: out = A @ pre2 ; 16 lanes/edge, 4 edges/iter ----------------

__global__ __launch_bounds__(256) void spmm2_k(const int* __restrict__ rp, const int* __restrict__ cd,
                                               const float* __restrict__ cv, const unsigned* __restrict__ P2,
                                               float* __restrict__ out) {
    const int g = threadIdx.x >> 6;
    const int lane = threadIdx.x & 63;
    const int node = blockIdx.x * 4 + g;
    if (node >= N_NODES) return;
    const int s = rp[node], e = rp[node + 1];
    const int f2 = lane & 15;      // uint index: feats 2*f2, 2*f2+1
    const int par = lane >> 4;     // 0..3
    float ax = 0.f, ay = 0.f;
    for (int i = s + par; i < e; i += 4) {
        int dst = cd[i];
        float v = cv[i];
        unsigned u = P2[(size_t)dst * 16 + f2];
        ax += v * bflo(u);
        ay += v * bfhi(u);
    }
    ax += __shfl_xor(ax, 16); ay += __shfl_xor(ay, 16);
    ax += __shfl_xor(ax, 32); ay += __shfl_xor(ay, 32);
    if (lane < 16) {
        float2 o; o.x = ax; o.y = ay;
        ((float2*)out)[(size_t)node * 16 + f2] = o;
    }
}

// ---------------- launch ----------------

extern "C" void kernel_launch(void* const* d_in, const int* in_sizes, int n_in,
                              void* d_out, int out_size, void* d_ws, size_t ws_size,
                              hipStream_t stream) {
    const float* x    = (const float*)d_in[0];
    const int* esrc   = (const int*)d_in[1];
    const int* edst   = (const int*)d_in[2];
    const float* ev   = (const float*)d_in[3];
    const float* W1   = (const float*)d_in[4];
    const float* W2   = (const float*)d_in[5];
    float* out        = (float*)d_out;

    // workspace layout; pre2b aliases pre1b (pre1b dead after spmm1)
    unsigned short* pre1b = (unsigned short*)d_ws;            // 6,400,000 ushort (12.8 MB)
    unsigned* hb          = (unsigned*)(pre1b + 6400000);     // 3,200,000 uint (12.8 MB)
    unsigned short* pre2b = pre1b;                            // 1,600,000 ushort (alias)
    float* csr_val        = (float*)(hb + 3200000);           // 800,000
    int* csr_dst          = (int*)(csr_val + 800000);         // 800,000
    int* row_ptr          = csr_dst + 800000;                 // 50,001 (pad 50,048)
    int* cursor           = row_ptr + 50048;
    int* bsum             = cursor + 50048;
    int* boff             = bsum + 256;
    unsigned short* W1t   = (unsigned short*)(boff + 256);    // 65,536 ushort

    hipLaunchKernelGGL(zero_k,     dim3(196),  dim3(256), 0, stream, cursor);
    hipLaunchKernelGGL(hist_k,     dim3(3125), dim3(256), 0, stream, esrc, cursor);
    hipLaunchKernelGGL(w1conv_k,   dim3(256),  dim3(256), 0, stream, W1, W1t);
    hipLaunchKernelGGL(scan_a,     dim3(196),  dim3(256), 0, stream, cursor, bsum);
    hipLaunchKernelGGL(scan_b,     dim3(1),    dim3(256), 0, stream, bsum, boff);
    hipLaunchKernelGGL(scan_c,     dim3(196),  dim3(256), 0, stream, cursor, boff, row_ptr, cursor);
    hipLaunchKernelGGL(scatter_k,  dim3(3125), dim3(256), 0, stream, esrc, edst, ev, cursor, csr_dst, csr_val);

    hipLaunchKernelGGL(gemm1_mfma, dim3(782),  dim3(256), 0, stream, x, W1t, pre1b);
    hipLaunchKernelGGL(spmm1_k,    dim3(12500),dim3(256), 0, stream, row_ptr, csr_dst, csr_val, (const unsigned*)pre1b, hb);
    hipLaunchKernelGGL(gemm2_k,    dim3(1563), dim3(256), 0, stream, hb, W2, pre2b);
    hipLaunchKernelGGL(spmm2_k,    dim3(12500),dim3(256), 0, stream, row_ptr, csr_dst, csr_val, (const unsigned*)pre2b, out);
}